// Round 13
// baseline (672.803 us; speedup 1.0000x reference)
//
#include <hip/hip_runtime.h>
#include <math.h>

namespace {

typedef short  short8 __attribute__((ext_vector_type(8)));
typedef float  f32x4  __attribute__((ext_vector_type(4)));

constexpr int BB = 2, CC = 64, HH = 256, WW = 512, OO = 64, KK = 9;
constexpr int PXB  = 128;   // pixel columns per block
constexpr int NGRP = 32;    // channel pairs
constexpr int CHW_F = 7 * WW;          // 7-row window covers rows h0..h0+1 jointly
constexpr int SSTR  = 42;              // Sb row stride in ushorts

__device__ __forceinline__ uint rne_bf16(float f) {
  uint u = __float_as_uint(f);
  return (u + 0x7fffu + ((u >> 16) & 1u)) >> 16;   // RNE, finite inputs
}

// Pack W[64o][64c][9k] f32 -> bf16 fragment order (r5 map, == r12 in-kernel build):
// wp[((g*4+ot)*64+lane)*8+j] = A[o=ot*16+(lane&15)][slot lg*8+j], slot->(c,kk):
// lg0: c=2g kk=j; lg1: c=2g kk=8(j=0) else 0; lg2: c=2g+1 kk=j; lg3: c=2g+1 kk=8.
__global__ void wpack_kernel(const float* __restrict__ wgt, ushort* __restrict__ wp) {
  int e = blockIdx.x * 256 + threadIdx.x;          // 0..65535
  int j = e & 7, lane = (e >> 3) & 63, ot = (e >> 9) & 3, g = e >> 11;
  int o  = ot * 16 + (lane & 15);
  int kp = g * 32 + ((lane >> 4) & 3) * 8 + j;
  int c = kp >> 4, kk = kp & 15;
  float v = (kk < 9) ? wgt[(o * 64 + c) * 9 + kk] : 0.0f;
  wp[e] = (ushort)rne_bf16(v);
}

__global__ __launch_bounds__(512, 4) void equiconv_mfma(
    const float* __restrict__ x, const float* __restrict__ wgt,
    const float* __restrict__ bias, float* __restrict__ out,
    const ushort* __restrict__ wp)
{
  __shared__ __align__(16) float  lbx[2][2 * CHW_F];  // [buf][ch*3584 + j*512 + col]
  __shared__ __align__(16) ushort Sb[256 * SSTR];     // [q][42]: slots 0..31

  const int tid  = threadIdx.x;
  const int wid  = tid >> 6, lane = tid & 63;
  const int q    = tid & 255;             // pixel id: row r = q>>7, col p = q&127
  const int r    = q >> 7;
  const int p    = q & 127;
  const int cc   = tid >> 8;              // channel parity for the gather
  const int w    = blockIdx.x * PXB + p;
  const int h0   = blockIdx.y * 2;        // top output row of this block
  const int h    = h0 + r;
  const int b    = blockIdx.z;

  // ---- geometry: verbatim bit-faithful f32 chain (PASSED r3/r4/r10-r12) ----
  int   jx[KK][4];
  float cw[KK][4];
  {
#pragma clang fp contract(off)
    const float TWO_PI_F = (float)(2.0 * M_PI);
    const float PI_F     = (float)M_PI;
    const float XS       = (float)(512.0 / (2.0 * M_PI));
    const float YS       = (float)(256.0 / M_PI);

    const float uf = (float)w, vf = (float)h;
    const float phi   = ((uf - 256.0f) / 512.0f) * TWO_PI_F;
    const float theta = ((-(vf - 128.0f)) / 256.0f) * PI_F;

    const float sp = (float)sin((double)phi);
    const float cp = (float)cos((double)phi);
    const float st = (float)sin((double)theta);
    const float ct = (float)cos((double)theta);

    const float R00 = cp;        const float R01 = sp * st;  const float R02 = sp * ct;
    /* R10 = 0 */                const float R11 = ct;       const float R12 = -st;
    const float R20 = -sp;       const float R21 = cp * st;  const float R22 = cp * ct;

    const double focal_d = 1.5 / tan(0.5 * (3.0 * (2.0 * M_PI / 512.0)));
    const float  focal_f = (float)focal_d;

    for (int k = 0; k < KK; ++k) {
      const float wgk = (float)(k % 3) + 0.5f - 1.5f;
      const float hgk = (float)(k / 3) + 0.5f - 1.5f;

      float rx0 = wgk / focal_f, ry0 = hgk / focal_f, rz0 = 1.0f;
      const float nrm = sqrtf(((rx0 * rx0) + (ry0 * ry0)) + (rz0 * rz0));
      rx0 = rx0 / nrm; ry0 = ry0 / nrm; rz0 = rz0 / nrm;

      const float r0 = ((R00 * rx0) + (R01 * ry0)) + (R02 * rz0);
      const float r1 =               ((R11 * ry0)) + (R12 * rz0);
      const float r2 = ((R20 * rx0) + (R21 * ry0)) + (R22 * rz0);

      const float phi2 = (float)atan2((double)r0, (double)r2);
      float r1c = r1;
      if (r1c >  1.0f) r1c =  1.0f;
      if (r1c < -1.0f) r1c = -1.0f;
      const float th2 = (float)asin((double)r1c);

      const float xx = (XS * phi2) + 256.0f;
      const float yy = (YS * th2)  + 128.0f;

      const float Ax = (float)(w + (k % 3) - 1);
      const float Ay = (float)(h + (k / 3) - 1);
      const float px = Ax + (xx - Ax);
      const float py = Ay + (yy - Ay);

      const float x0f = floorf(px), y0f = floorf(py);
      const float wx1 = px - x0f,   wy1 = py - y0f;
      const int ix0 = (int)x0f, iy0 = (int)y0f;
      const int ix1 = ix0 + 1,  iy1 = iy0 + 1;
      const bool vx0 = (ix0 >= 0) && (ix0 < WW);
      const bool vx1 = (ix1 >= 0) && (ix1 < WW);
      const bool vy0 = (iy0 >= 0) && (iy0 < HH);
      const bool vy1 = (iy1 >= 0) && (iy1 < HH);
      const int cx0 = min(max(ix0, 0), WW - 1);
      const int cx1 = min(max(ix1, 0), WW - 1);
      const int cy0 = min(max(iy0, 0), HH - 1);
      const int cy1 = min(max(iy1, 0), HH - 1);
      // 7-row window: LDS row j holds plane row clamp(h0-2+j); for row r pixel,
      // j0 = cy0-h0+2 in [r, r+4], j1 in [r+1, r+5] -> all within 0..6.
      const int j0 = cy0 - h0 + 2;
      const int j1 = cy1 - h0 + 2;
      jx[k][0] = j0 * WW + cx0;
      jx[k][1] = j0 * WW + cx1;
      jx[k][2] = j1 * WW + cx0;
      jx[k][3] = j1 * WW + cx1;
      const float wy0f = 1.0f - wy1, wx0f = 1.0f - wx1;
      cw[k][0] = (wy0f * wx0f) * ((vy0 && vx0) ? 1.0f : 0.0f);
      cw[k][1] = (wy0f * wx1)  * ((vy0 && vx1) ? 1.0f : 0.0f);
      cw[k][2] = (wy1 * wx0f)  * ((vy1 && vx0) ? 1.0f : 0.0f);
      cw[k][3] = (wy1 * wx1)   * ((vy1 && vx1) ? 1.0f : 0.0f);
    }
  }

  // zero Sb once (zero k-slots stay zero forever; A-side zeros also kill them)
  {
    uint* S32 = (uint*)Sb;                      // 256*21 = 5376 u32
#pragma unroll
    for (int i = 0; i < 11; ++i) {
      const int idx = tid + 512 * i;
      if (idx < (256 * SSTR) / 2) S32[idx] = 0u;
    }
  }

  // stage 2 channels for group g2 into buf bi: 28 real 1KB chunks + 4 benign
  // duplicates (wave 7 re-stages chunks 0-3: same src, same dest, same data)
  // so every wave issues exactly 4 global_load_lds -> uniform vmcnt(4).
  auto stage = [&](int bi, int g2) {
#pragma unroll
    for (int i = 0; i < 4; ++i) {
      const int ci  = wid * 4 + i;              // 0..31, wave-uniform
      const int cci = (ci < 28) ? ci : (ci - 28);
      const int ch  = cci / 14, rem = cci % 14, j = rem >> 1, half = rem & 1;
      const int srow = min(max(h0 - 2 + j, 0), HH - 1);
      const int chan = g2 * 2 + ch;
      const float* src = x + (((size_t)b * CC + chan) * HH + srow) * WW + half * 256 + lane * 4;
      __builtin_amdgcn_global_load_lds(
          (const __attribute__((address_space(1))) void*)src,
          (__attribute__((address_space(3))) void*)&lbx[bi][ch * CHW_F + j * 512 + half * 256],
          16, 0, 0);
    }
  };

  f32x4 acc[4][2];
#pragma unroll
  for (int ot = 0; ot < 4; ++ot)
#pragma unroll
    for (int pt = 0; pt < 2; ++pt) acc[ot][pt] = (f32x4){0.f, 0.f, 0.f, 0.f};

  stage(0, 0);   // prologue prefetch

#pragma unroll 1
  for (int g = 0; g < NGRP; ++g) {
    const int bi = g & 1;

    // A fragments: wpack path (4 x dwordx4) or in-kernel build (r12-proven,
    // bit-identical values). Pinned BEFORE stage(g+1) so vmcnt(4) always
    // drains them (vmcnt retires oldest-first).
    short8 A[4];
    if (wp) {
#pragma unroll
      for (int ot = 0; ot < 4; ++ot)
        A[ot] = *(const short8*)(wp + ((size_t)(g * 4 + ot) * 64 + lane) * 8);
    } else {
      const int lg = lane >> 4;
      const int c  = g * 2 + (lg >> 1);
#pragma unroll
      for (int ot = 0; ot < 4; ++ot) {
        const int o = ot * 16 + (lane & 15);
        const float* wp9 = wgt + ((size_t)o * 64 + c) * 9;
        short8 a;
        if ((lg & 1) == 0) {
#pragma unroll
          for (int j = 0; j < 8; ++j) a[j] = (short)(ushort)rne_bf16(wp9[j]);
        } else {
          a = (short8){0, 0, 0, 0, 0, 0, 0, 0};
          a[0] = (short)(ushort)rne_bf16(wp9[8]);
        }
        A[ot] = a;
      }
    }
    __builtin_amdgcn_sched_barrier(0);          // pin A-loads before stage(g+1)

    if (g < NGRP - 1) {
      stage(bi ^ 1, g + 1);                     // prefetch next group's windows
      asm volatile("s_waitcnt vmcnt(4)" ::: "memory");   // drain stage(g)+A; keep stage(g+1)
    } else {
      asm volatile("s_waitcnt vmcnt(0)" ::: "memory");
    }
    __builtin_amdgcn_sched_barrier(0);
    __builtin_amdgcn_s_barrier();               // BARRIER A: lbx[bi] visible everywhere
    __builtin_amdgcn_sched_barrier(0);

    // ---- gather channel 2g+cc for pixel q (verbatim r10-r12, PASSED) ----
    {
      const float* Lc = &lbx[bi][cc * CHW_F];
      float s[KK];
#pragma unroll
      for (int k = 0; k < KK; ++k) {
        s[k] = fmaf(cw[k][3], Lc[jx[k][3]],
               fmaf(cw[k][2], Lc[jx[k][2]],
               fmaf(cw[k][1], Lc[jx[k][1]],
                    cw[k][0] * Lc[jx[k][0]])));
      }
      const uint b0 = rne_bf16(s[0]), b1 = rne_bf16(s[1]), b2 = rne_bf16(s[2]);
      const uint b3 = rne_bf16(s[3]), b4 = rne_bf16(s[4]), b5 = rne_bf16(s[5]);
      const uint b6 = rne_bf16(s[6]), b7 = rne_bf16(s[7]), b8 = rne_bf16(s[8]);
      uint2* Sr = (uint2*)(Sb + q * SSTR + cc * 16);
      Sr[0] = make_uint2(b0 | (b1 << 16), b2 | (b3 << 16));
      Sr[1] = make_uint2(b4 | (b5 << 16), b6 | (b7 << 16));
      Sb[q * SSTR + cc * 16 + 8] = (ushort)b8;
    }

    asm volatile("s_waitcnt lgkmcnt(0)" ::: "memory");
    __builtin_amdgcn_sched_barrier(0);
    __builtin_amdgcn_s_barrier();               // BARRIER B: Sb(g) complete
    __builtin_amdgcn_sched_barrier(0);

    // ---- B fragments + MFMA, scheduler-pinned (rule #18, r11/r12-proven) ----
    // Single-buffer Sb safety: Bfr ds_reads drain at the lgkmcnt(0) below,
    // before this wave reaches BARRIER A(g+1); Sb(g+1) writes happen only
    // after BARRIER A(g+1). lbx reads drain before BARRIER B(g); next writes
    // to this buf are stage(g+2) issued after BARRIER B(g).
    short8 Bfr[2];
#pragma unroll
    for (int pt = 0; pt < 2; ++pt) {
      const int prow = wid * 32 + pt * 16 + (lane & 15);
      Bfr[pt] = *(const short8*)(Sb + prow * SSTR + ((lane >> 4) & 3) * 8);
    }
    asm volatile("s_waitcnt lgkmcnt(0)" ::: "memory");
    __builtin_amdgcn_sched_barrier(0);          // MFMA must not hoist above the wait
#pragma unroll
    for (int ot = 0; ot < 4; ++ot)
#pragma unroll
      for (int pt = 0; pt < 2; ++pt)
        acc[ot][pt] = __builtin_amdgcn_mfma_f32_16x16x32_bf16(A[ot], Bfr[pt], acc[ot][pt], 0, 0, 0);
    __builtin_amdgcn_sched_barrier(0);          // nothing sinks/hoists across the cluster
  }

  // ---- epilogue: D row=(lane>>4)*4+rr, col=lane&15 (m89 layout, proven) ----
#pragma unroll
  for (int ot = 0; ot < 4; ++ot) {
    const int ob = ot * 16 + ((lane >> 4) & 3) * 4;
#pragma unroll
    for (int pt = 0; pt < 2; ++pt) {
      const int wq   = wid * 32 + pt * 16 + (lane & 15);   // pixel id 0..255
      const int rowo = h0 + (wq >> 7);
      const int colo = blockIdx.x * PXB + (wq & 127);
#pragma unroll
      for (int rr = 0; rr < 4; ++rr)
        out[(((size_t)b * OO + (ob + rr)) * HH + rowo) * WW + colo] = acc[ot][pt][rr] + bias[ob + rr];
    }
  }
}

} // namespace

extern "C" void kernel_launch(void* const* d_in, const int* in_sizes, int n_in,
                              void* d_out, int out_size, void* d_ws, size_t ws_size,
                              hipStream_t stream) {
  const float* x      = (const float*)d_in[0];
  const float* weight = (const float*)d_in[1];
  const float* bias   = (const float*)d_in[2];
  float* out          = (float*)d_out;

  const bool use_ws = (d_ws != nullptr && ws_size >= 131072);
  ushort* wp = use_ws ? (ushort*)d_ws : nullptr;
  if (use_ws)
    hipLaunchKernelGGL(wpack_kernel, dim3(256), dim3(256), 0, stream, weight, wp);

  dim3 grid(WW / PXB, HH / 2, BB);              // 4 x 128 x 2
  hipLaunchKernelGGL(equiconv_mfma, grid, dim3(512), 0, stream,
                     x, weight, bias, out, (const ushort*)wp);
}